// Round 1
// baseline (165.002 us; speedup 1.0000x reference)
//
#include <hip/hip_runtime.h>

// ---------------------------------------------------------------------------
// FEM assembly: dense stiffness (ndof x ndof) + residual (ndof)
// Inputs (in_sizes order):
//  0 xcoord [nnode] f32      1 ycoord [nnode] f32    2 connect [nelem*3] i32
//  3 elem_material [nelem]   4 dload_elem [nd] i32   5 dload_face [nd] i32
//  6 dload_tx [nd] f32       7 dload_ty [nd] f32     8 fix_node [nf] i32
//  9 fix_dof [nf] i32       10 fix_val [nf] f32
// Output: stiff (ndof*ndof f32) ++ resid (ndof f32)
// ---------------------------------------------------------------------------

__global__ void assemble_kernel(const float* __restrict__ x,
                                const float* __restrict__ y,
                                const int* __restrict__ connect,
                                const float* __restrict__ mat,
                                float* __restrict__ stiff,
                                int nelem, int ndof) {
    int e = blockIdx.x * blockDim.x + threadIdx.x;
    if (e >= nelem) return;

    int a = connect[3 * e + 0];
    int b = connect[3 * e + 1];
    int c = connect[3 * e + 2];

    float xa = x[a], xb = x[b], xc = x[c];
    float ya = y[a], yb = y[b], yc = y[c];

    float den_a = (ya - yb) * (xc - xb) - (xa - xb) * (yc - yb);
    float den_b = (yb - yc) * (xa - xc) - (xb - xc) * (ya - yc);
    float den_c = (yc - ya) * (xb - xa) - (xc - xa) * (yb - ya);

    float nax = -(yc - yb) / den_a;
    float nay =  (xc - xb) / den_a;
    float nbx = -(ya - yc) / den_b;
    float nby =  (xa - xc) / den_b;
    float ncx = -(yb - ya) / den_c;
    float ncy =  (xb - xa) / den_c;

    float area = 0.5f * fabsf((xb - xa) * (yc - ya) - (xc - xa) * (yb - ya));

    // material matrix (fp32, same arithmetic as reference create_Dmat)
    float nu, E;
    if (mat[e] > 0.5f) { nu = 0.33f; E = 69.0f; }   // aluminium
    else               { nu = 0.30f; E = 200.0f; }  // steel
    float cc  = E / ((1.0f + nu) * (1.0f - 2.0f * nu));
    float d00 = cc * (1.0f - nu);
    float d01 = cc * nu;
    float d22 = cc * (1.0f - 2.0f * nu) * 0.5f;

    // B rows (3 x 6)
    float B0[6] = { nax, 0.0f, nbx, 0.0f, ncx, 0.0f };
    float B1[6] = { 0.0f, nay, 0.0f, nby, 0.0f, ncy };
    float B2[6] = { nay,  nax, nby,  nbx, ncy,  ncx };

    // C = D * B  (3 x 6)
    float C0[6], C1[6], C2[6];
#pragma unroll
    for (int j = 0; j < 6; ++j) {
        C0[j] = d00 * B0[j] + d01 * B1[j];
        C1[j] = d01 * B0[j] + d00 * B1[j];
        C2[j] = d22 * B2[j];
    }

    int dof[6] = { 2 * a, 2 * a + 1, 2 * b, 2 * b + 1, 2 * c, 2 * c + 1 };

#pragma unroll
    for (int i = 0; i < 6; ++i) {
        float* rowp = stiff + (size_t)dof[i] * (size_t)ndof;
#pragma unroll
        for (int j = 0; j < 6; ++j) {
            float kij = area * (B0[i] * C0[j] + B1[i] * C1[j] + B2[i] * C2[j]);
            atomicAdd(rowp + dof[j], kij);
        }
    }
}

__global__ void traction_kernel(const float* __restrict__ x,
                                const float* __restrict__ y,
                                const int* __restrict__ connect,
                                const int* __restrict__ dload_elem,
                                const int* __restrict__ dload_face,
                                const float* __restrict__ tx,
                                const float* __restrict__ ty,
                                float* __restrict__ resid,
                                int ndload) {
    int i = blockIdx.x * blockDim.x + threadIdx.x;
    if (i >= ndload) return;
    int e = dload_elem[i];
    int f = dload_face[i];
    // pointer = [1,2,0]
    int f2 = (f == 0) ? 1 : (f == 1 ? 2 : 0);
    int a = connect[3 * e + f];
    int b = connect[3 * e + f2];
    float dx = x[a] - x[b];
    float dy = y[a] - y[b];
    float hl = 0.5f * sqrtf(dx * dx + dy * dy);
    float vx = tx[i] * hl;
    float vy = ty[i] * hl;
    atomicAdd(&resid[2 * a + 0], vx);
    atomicAdd(&resid[2 * a + 1], vy);
    atomicAdd(&resid[2 * b + 0], vx);
    atomicAdd(&resid[2 * b + 1], vy);
}

// One block per fix: zero the whole row. Idempotent, so concurrent duplicate
// rows are safe. Diagonal/resid set happens in a SEPARATE kernel (stream
// ordering) to avoid the race where a duplicate fix's row-zero lands after
// another fix's diag=1 store.
__global__ void fix_zero_rows_kernel(const int* __restrict__ fix_node,
                                     const int* __restrict__ fix_dof,
                                     float* __restrict__ stiff,
                                     int ndof) {
    int i = blockIdx.x;  // fix index
    int rw = 2 * fix_node[i] + fix_dof[i];
    float* row = stiff + (size_t)rw * (size_t)ndof;
    for (int j = threadIdx.x; j < ndof; j += blockDim.x) row[j] = 0.0f;
}

__global__ void fix_set_kernel(const int* __restrict__ fix_node,
                               const int* __restrict__ fix_dof,
                               const float* __restrict__ fix_val,
                               float* __restrict__ stiff,
                               float* __restrict__ resid,
                               int nfix, int ndof) {
    int i = blockIdx.x * blockDim.x + threadIdx.x;
    if (i >= nfix) return;
    int rw = 2 * fix_node[i] + fix_dof[i];
    stiff[(size_t)rw * (size_t)ndof + rw] = 1.0f;  // same value for dup rows: benign
    // resid[rw] = fix_val[i], last-occurrence-wins (NumPy assignment semantics)
    bool last = true;
    for (int j = i + 1; j < nfix; ++j) {
        if (2 * fix_node[j] + fix_dof[j] == rw) { last = false; break; }
    }
    if (last) resid[rw] = fix_val[i];
}

extern "C" void kernel_launch(void* const* d_in, const int* in_sizes, int n_in,
                              void* d_out, int out_size, void* d_ws, size_t ws_size,
                              hipStream_t stream) {
    const float* xcoord   = (const float*)d_in[0];
    const float* ycoord   = (const float*)d_in[1];
    const int*   connect  = (const int*)d_in[2];
    const float* emat     = (const float*)d_in[3];
    const int*   dl_elem  = (const int*)d_in[4];
    const int*   dl_face  = (const int*)d_in[5];
    const float* dl_tx    = (const float*)d_in[6];
    const float* dl_ty    = (const float*)d_in[7];
    const int*   fix_node = (const int*)d_in[8];
    const int*   fix_dof  = (const int*)d_in[9];
    const float* fix_val  = (const float*)d_in[10];

    const int nnode  = in_sizes[0];
    const int ndof   = 2 * nnode;
    const int nelem  = in_sizes[3];
    const int ndload = in_sizes[4];
    const int nfix   = in_sizes[8];

    float* stiff = (float*)d_out;
    float* resid = stiff + (size_t)ndof * (size_t)ndof;

    // 1) zero the whole output (stiff + resid): the dominant 576 MB write
    hipMemsetAsync(d_out, 0, (size_t)out_size * sizeof(float), stream);

    // 2) element stiffness assembly (atomic scatter-add)
    {
        int threads = 256;
        int blocks = (nelem + threads - 1) / threads;
        assemble_kernel<<<blocks, threads, 0, stream>>>(
            xcoord, ycoord, connect, emat, stiff, nelem, ndof);
    }

    // 3) traction loads into resid
    {
        int threads = 256;
        int blocks = (ndload + threads - 1) / threads;
        traction_kernel<<<blocks, threads, 0, stream>>>(
            xcoord, ycoord, connect, dl_elem, dl_face, dl_tx, dl_ty,
            resid, ndload);
    }

    // 4) zero fixed rows (after assembly; one block per fix)
    fix_zero_rows_kernel<<<nfix, 256, 0, stream>>>(fix_node, fix_dof, stiff, ndof);

    // 5) unit diagonal + prescribed resid values (last-occurrence-wins)
    {
        int threads = 256;
        int blocks = (nfix + threads - 1) / threads;
        fix_set_kernel<<<blocks, threads, 0, stream>>>(
            fix_node, fix_dof, fix_val, stiff, resid, nfix, ndof);
    }
}

// Round 2
// 150.173 us; speedup vs baseline: 1.0987x; 1.0987x over previous
//
#include <hip/hip_runtime.h>

// ---------------------------------------------------------------------------
// FEM assembly, single-pass gather formulation.
// Output: stiff (ndof*ndof f32) ++ resid (ndof f32), ndof = 2*nnode.
//
// Instead of memset(576MB) + atomic scatter + BC row-zero (3 full/partial
// passes over stiff), we build a node->element adjacency once (tiny), then
// write each stiffness row EXACTLY ONCE: one block per row, row staged in
// 48 KB dynamic LDS (zero -> gather ~6 element contributions via LDS atomics,
// or diag=1 for fixed rows -> coalesced float4 stream-out).
// ---------------------------------------------------------------------------

#define ADJ_CAP 64   // max elements per node; E[deg]=6 (Poisson), P(>64)~0

// ws layout (ints): [cnt: nnode][mask: ndof][adj: nnode*ADJ_CAP]

__global__ void build_adj_kernel(const int* __restrict__ connect, int nelem,
                                 const int* __restrict__ fix_node,
                                 const int* __restrict__ fix_dof, int nfix,
                                 int* __restrict__ cnt,
                                 int* __restrict__ mask,
                                 int* __restrict__ adj) {
    int t = blockIdx.x * blockDim.x + threadIdx.x;
    if (t < nelem) {
#pragma unroll
        for (int v = 0; v < 3; ++v) {
            int n = connect[3 * t + v];
            int slot = atomicAdd(&cnt[n], 1);
            if (slot < ADJ_CAP) adj[n * ADJ_CAP + slot] = (t << 2) | v;
        }
    }
    if (t < nfix) {
        mask[2 * fix_node[t] + fix_dof[t]] = 1;
    }
}

__global__ __launch_bounds__(256) void row_write_kernel(
        const float* __restrict__ x, const float* __restrict__ y,
        const int* __restrict__ connect, const float* __restrict__ mat,
        const int* __restrict__ cnt, const int* __restrict__ mask,
        const int* __restrict__ adj,
        float* __restrict__ stiff, int ndof) {
    extern __shared__ float row[];   // ndof floats
    const int r = blockIdx.x;        // stiffness row
    const int tid = threadIdx.x;
    const int n = r >> 1;            // node
    const int d = r & 1;             // dof direction

    // zero the LDS row (ndof % 4 == 0 here)
    float4* row4 = (float4*)row;
    const int n4 = ndof >> 2;
    for (int i = tid; i < n4; i += 256) row4[i] = make_float4(0.f, 0.f, 0.f, 0.f);
    __syncthreads();

    const bool is_fixed = (mask[r] != 0);
    if (is_fixed) {
        if (tid == 0) row[r] = 1.0f;   // BC: zero row, unit diagonal
    } else {
        int deg = cnt[n];
        if (deg > ADJ_CAP) deg = ADJ_CAP;
        if (tid < deg) {
            const int packed = adj[n * ADJ_CAP + tid];
            const int e  = packed >> 2;
            const int li = packed & 3;   // local index of node n in element e

            const int a = connect[3 * e + 0];
            const int b = connect[3 * e + 1];
            const int c = connect[3 * e + 2];
            const float xa = x[a], xb = x[b], xc = x[c];
            const float ya = y[a], yb = y[b], yc = y[c];

            const float den_a = (ya - yb) * (xc - xb) - (xa - xb) * (yc - yb);
            const float den_b = (yb - yc) * (xa - xc) - (xb - xc) * (ya - yc);
            const float den_c = (yc - ya) * (xb - xa) - (xc - xa) * (yb - ya);

            const float nax = -(yc - yb) / den_a;
            const float nay =  (xc - xb) / den_a;
            const float nbx = -(ya - yc) / den_b;
            const float nby =  (xa - xc) / den_b;
            const float ncx = -(yb - ya) / den_c;
            const float ncy =  (xb - xa) / den_c;

            const float area = 0.5f * fabsf((xb - xa) * (yc - ya) -
                                            (xc - xa) * (yb - ya));

            float nu, E;
            if (mat[e] > 0.5f) { nu = 0.33f; E = 69.0f; }
            else               { nu = 0.30f; E = 200.0f; }
            const float cc  = E / ((1.0f + nu) * (1.0f - 2.0f * nu));
            const float d00 = cc * (1.0f - nu);
            const float d01 = cc * nu;
            const float d22 = cc * (1.0f - 2.0f * nu) * 0.5f;

            // B rows (compile-time indexed)
            const float B0[6] = { nax, 0.f, nbx, 0.f, ncx, 0.f };
            const float B1[6] = { 0.f, nay, 0.f, nby, 0.f, ncy };
            const float B2[6] = { nay, nax, nby, nbx, ncy, ncx };

            // this row's B entries: i = 2*li + d (select, no runtime array idx)
            const float nx = (li == 0) ? nax : (li == 1) ? nbx : ncx;
            const float ny = (li == 0) ? nay : (li == 1) ? nby : ncy;
            const float Bi0 = (d == 0) ? nx : 0.f;
            const float Bi1 = (d == 0) ? 0.f : ny;
            const float Bi2 = (d == 0) ? ny : nx;

            const int dof[6] = { 2 * a, 2 * a + 1, 2 * b, 2 * b + 1,
                                 2 * c, 2 * c + 1 };
#pragma unroll
            for (int j = 0; j < 6; ++j) {
                const float C0j = d00 * B0[j] + d01 * B1[j];
                const float C1j = d01 * B0[j] + d00 * B1[j];
                const float C2j = d22 * B2[j];
                const float val = area * (Bi0 * C0j + Bi1 * C1j + Bi2 * C2j);
                atomicAdd(&row[dof[j]], val);   // LDS atomic (ds_add_f32)
            }
        }
    }
    __syncthreads();

    // stream LDS row -> global, coalesced float4
    float4* dst = (float4*)(stiff + (size_t)r * (size_t)ndof);
    for (int i = tid; i < n4; i += 256) dst[i] = row4[i];
}

__global__ void traction_kernel(const float* __restrict__ x,
                                const float* __restrict__ y,
                                const int* __restrict__ connect,
                                const int* __restrict__ dload_elem,
                                const int* __restrict__ dload_face,
                                const float* __restrict__ tx,
                                const float* __restrict__ ty,
                                float* __restrict__ resid,
                                int ndload) {
    int i = blockIdx.x * blockDim.x + threadIdx.x;
    if (i >= ndload) return;
    int e = dload_elem[i];
    int f = dload_face[i];
    int f2 = (f == 0) ? 1 : (f == 1 ? 2 : 0);   // pointer = [1,2,0]
    int a = connect[3 * e + f];
    int b = connect[3 * e + f2];
    float dx = x[a] - x[b];
    float dy = y[a] - y[b];
    float hl = 0.5f * sqrtf(dx * dx + dy * dy);
    float vx = tx[i] * hl;
    float vy = ty[i] * hl;
    atomicAdd(&resid[2 * a + 0], vx);
    atomicAdd(&resid[2 * a + 1], vy);
    atomicAdd(&resid[2 * b + 0], vx);
    atomicAdd(&resid[2 * b + 1], vy);
}

__global__ void fix_resid_kernel(const int* __restrict__ fix_node,
                                 const int* __restrict__ fix_dof,
                                 const float* __restrict__ fix_val,
                                 float* __restrict__ resid, int nfix) {
    int i = blockIdx.x * blockDim.x + threadIdx.x;
    if (i >= nfix) return;
    int rw = 2 * fix_node[i] + fix_dof[i];
    // last-occurrence-wins (NumPy fancy-assignment semantics)
    bool last = true;
    for (int j = i + 1; j < nfix; ++j) {
        if (2 * fix_node[j] + fix_dof[j] == rw) { last = false; break; }
    }
    if (last) resid[rw] = fix_val[i];
}

extern "C" void kernel_launch(void* const* d_in, const int* in_sizes, int n_in,
                              void* d_out, int out_size, void* d_ws, size_t ws_size,
                              hipStream_t stream) {
    const float* xcoord   = (const float*)d_in[0];
    const float* ycoord   = (const float*)d_in[1];
    const int*   connect  = (const int*)d_in[2];
    const float* emat     = (const float*)d_in[3];
    const int*   dl_elem  = (const int*)d_in[4];
    const int*   dl_face  = (const int*)d_in[5];
    const float* dl_tx    = (const float*)d_in[6];
    const float* dl_ty    = (const float*)d_in[7];
    const int*   fix_node = (const int*)d_in[8];
    const int*   fix_dof  = (const int*)d_in[9];
    const float* fix_val  = (const float*)d_in[10];

    const int nnode  = in_sizes[0];
    const int ndof   = 2 * nnode;
    const int nelem  = in_sizes[3];
    const int ndload = in_sizes[4];
    const int nfix   = in_sizes[8];

    float* stiff = (float*)d_out;
    float* resid = stiff + (size_t)ndof * (size_t)ndof;

    // ws layout (ints): cnt[nnode] | mask[ndof] | adj[nnode*ADJ_CAP]
    int* cnt  = (int*)d_ws;
    int* mask = cnt + nnode;
    int* adj  = mask + ndof;

    // zero cnt+mask (72 KB) and resid (48 KB)
    hipMemsetAsync(d_ws, 0, (size_t)(nnode + ndof) * sizeof(int), stream);
    hipMemsetAsync(resid, 0, (size_t)ndof * sizeof(float), stream);

    // adjacency + fixed-row mask
    {
        int threads = 256;
        int blocks = (nelem + threads - 1) / threads;
        build_adj_kernel<<<blocks, threads, 0, stream>>>(
            connect, nelem, fix_node, fix_dof, nfix, cnt, mask, adj);
    }

    // one block per stiffness row: single full write pass over stiff
    row_write_kernel<<<ndof, 256, (size_t)ndof * sizeof(float), stream>>>(
        xcoord, ycoord, connect, emat, cnt, mask, adj, stiff, ndof);

    // residual: traction loads then prescribed values
    {
        int threads = 256;
        int blocks = (ndload + threads - 1) / threads;
        traction_kernel<<<blocks, threads, 0, stream>>>(
            xcoord, ycoord, connect, dl_elem, dl_face, dl_tx, dl_ty,
            resid, ndload);
    }
    {
        int threads = 256;
        int blocks = (nfix + threads - 1) / threads;
        fix_resid_kernel<<<blocks, threads, 0, stream>>>(
            fix_node, fix_dof, fix_val, resid, nfix);
    }
}